// Round 8
// baseline (237.085 us; speedup 1.0000x reference)
//
#include <hip/hip_runtime.h>
#include <math.h>

#define NSEG 7320
#define NLON 120
#define HIDN 128
#define ECH  16     // entries per k2 block chunk (R0-proven)
#define NCH  33     // 33*16 = 528-entry cap per row (max row ~520; validated)

// ---------------------------------------------------------------------------
// K1 (R8 rewrite): tile-GEMM. One block = 64 points x 256 threads.
// Phase 1 (t<64): LN0 per point (global loads coalesced across lanes),
// normalized tile -> LDS xs[c][p] (16 KB). Phase 2 (4 waves): wave og owns
// 48 of 192 output channels; each thread reg-caches its point's column
// xv[64] from LDS ONCE, then 48x64 FMA with scalar-broadcast weights.
// This kills the session-long disease: all prior k1/trio variants re-read
// the K=64 input column from GLOBAL per pass (~500cy exposed per wave at
// 5-25% VALUBusy, ~145us combined for ~6us of VALU work).
// q pre-scaled by 1/sqrt(DH)=0.25.
// grp 1: meta {hi*120, dl, qw bits, ho} + CSR offsets + zero num/den.
// ---------------------------------------------------------------------------
__global__ __launch_bounds__(256) void k1_ln_qkv(
    const float* __restrict__ x,  const float* __restrict__ wq,
    const float* __restrict__ wk, const float* __restrict__ wv,
    const float* __restrict__ g,  const float* __restrict__ b,
    const int* __restrict__ out_idx, const int* __restrict__ in_idx,
    const float* __restrict__ qw, int E,
    float* __restrict__ q_pl, float* __restrict__ k_pl, float* __restrict__ v_pl,
    int* __restrict__ row_start, int4* __restrict__ meta,
    float4* __restrict__ zbase)
{
    const int t    = threadIdx.x;          // 0..255
    const int tile = blockIdx.x;           // 0..114

    if (blockIdx.y == 1) {                 // meta + row_start + zero num/den
        for (int e = tile * 256 + t; e < E; e += 115 * 256) {
            int ho = out_idx[e * NLON] / NLON;
            if (e == 0) {
                row_start[ho] = 0;
            } else {
                int hp = out_idx[(e - 1) * NLON] / NLON;
                if (hp != ho) row_start[ho] = e;
            }
            if (e == E - 1) row_start[ho + 1] = E;
            int i0 = in_idx[e * NLON];     // wo = 0 column: hi*120 + dl
            int hi = i0 / NLON;
            int dl = i0 - hi * NLON;
            meta[e] = make_int4(hi * NLON, dl, __float_as_int(qw[i0]), ho);
        }
        const int n4 = (68 * NSEG) / 4;    // num[64][NSEG] + den[4][NSEG]
        for (int i = tile * 256 + t; i < n4; i += 115 * 256)
            zbase[i] = make_float4(0.f, 0.f, 0.f, 0.f);
        return;
    }

    __shared__ float xs[64][64];           // [c][p] 16 KB
    const int n0 = tile * 64;

    if (t < 64) {                          // LN0 for point p = t
        const int nc = (n0 + t < NSEG) ? (n0 + t) : (NSEG - 1);
        float xv[64];
        float s = 0.f, s2 = 0.f;
#pragma unroll
        for (int c = 0; c < 64; ++c) {
            float v = x[c * NSEG + nc];
            xv[c] = v; s += v; s2 += v * v;
        }
        float mean = s * 0.015625f;
        float var  = s2 * 0.015625f - mean * mean;
        float rstd = rsqrtf(var + 1e-6f);
#pragma unroll
        for (int c = 0; c < 64; ++c)
            xs[c][t] = (xv[c] - mean) * rstd * g[c] + b[c];
    }
    __syncthreads();

    const int og = t >> 6;                 // wave id 0..3
    const int p  = t & 63;
    const int n  = n0 + p;
    const bool ok = n < NSEG;

    float xv[64];
#pragma unroll
    for (int c = 0; c < 64; ++c) xv[c] = xs[c][p];   // conflict-free (2/bank)

#pragma unroll 4
    for (int j = 0; j < 48; ++j) {
        const int o  = og * 48 + j;        // 0..191
        const int mm = o >> 6;             // 0=q 1=k 2=v (scalar per j)
        const int oc = o & 63;
        const float* __restrict__ w = (mm == 0) ? wq : (mm == 1) ? wk : wv;
        float acc = 0.f;
#pragma unroll
        for (int c = 0; c < 64; ++c) acc += w[oc * 64 + c] * xv[c];
        if (ok) {
            float* __restrict__ dst = (mm == 0) ? q_pl : (mm == 1) ? k_pl : v_pl;
            dst[oc * NSEG + n] = (mm == 0) ? acc * 0.25f : acc;
        }
    }
}

// ---------------------------------------------------------------------------
// K2: fused scores + PV — EXACT R0 structure (43.3us; rewrites R1-R5 all
// regressed: the compiler's pressure-minimizing scheduler serializes any
// wide-load variant to 32 VGPRs, and waves/atomics/ILP were each falsified
// as bottlenecks). One HEAD per block, 128 thr, lane = wo; 33 independent
// scalar loads/entry are the latency hiding. Epilogue: 16 num + 1 den
// atomics/lane. No-max softmax (scores O(+-8); validated).
// ---------------------------------------------------------------------------
__global__ __launch_bounds__(128) void k2_attn(
    const float* __restrict__ q_pl, const float* __restrict__ k_pl,
    const float* __restrict__ v_pl,
    const int4* __restrict__ meta,  const int* __restrict__ row_start,
    float* __restrict__ num, float* __restrict__ den)
{
    const int wo  = threadIdx.x;           // 0..127
    const bool aw = wo < NLON;
    const int woc = aw ? wo : (NLON - 1);
    const int ho  = blockIdx.x;
    const int head = blockIdx.z;           // 0..3
    const int cb  = head * 16;

    int e0 = __builtin_amdgcn_readfirstlane(row_start[ho]);
    int e1 = __builtin_amdgcn_readfirstlane(row_start[ho + 1]);
    int eb = e0 + blockIdx.y * ECH;
    if (eb >= e1) return;
    int ee = eb + ECH; if (ee > e1) ee = e1;

    const int segc = ho * NLON + woc;
    const float* __restrict__ qb = q_pl + (size_t)cb * NSEG;
    const float* __restrict__ kb = k_pl + (size_t)cb * NSEG;
    const float* __restrict__ vb = v_pl + (size_t)cb * NSEG;

    float qreg[16];
#pragma unroll
    for (int c = 0; c < 16; ++c) qreg[c] = qb[c * NSEG + segc];

    float acc[16];
#pragma unroll
    for (int c = 0; c < 16; ++c) acc[c] = 0.f;
    float dh = 0.f;

#pragma unroll 2
    for (int e = eb; e < ee; ++e) {
        int4 mt = meta[e];
        int dlw = mt.y + woc; if (dlw >= NLON) dlw -= NLON;
        const float* __restrict__ kp = kb + (mt.x + dlw);
        const float* __restrict__ vp = vb + (mt.x + dlw);

        float sa = 0.f, sb = 0.f;
#pragma unroll
        for (int c = 0; c < 8; ++c)  sa += qreg[c]     * kp[c * NSEG];
#pragma unroll
        for (int c = 0; c < 8; ++c)  sb += qreg[8 + c] * kp[(8 + c) * NSEG];

        float qwv = aw ? __int_as_float(mt.z) : 0.f;
        float a = __expf(sa + sb) * qwv;
        dh += a;

#pragma unroll
        for (int c = 0; c < 16; ++c) acc[c] = fmaf(a, vp[c * NSEG], acc[c]);
    }

    if (aw) {
        const int seg = ho * NLON + wo;
#pragma unroll
        for (int c = 0; c < 16; ++c) atomicAdd(&num[(cb + c) * NSEG + seg], acc[c]);
        atomicAdd(&den[head * NSEG + seg], dh);
    }
}

// ---------------------------------------------------------------------------
// KT (R8): fused epilogue — att=num/den -> Wo+residual -> LN1 -> W1+gelu ->
// W2+b2+residual. All dependencies are point-local, so one block owns a
// 64-point tile end-to-end; x1 and m_act live only in LDS (their global
// arrays are GONE). 256 thr; GEMM phases: wave og owns a channel chunk,
// each thread reg-caches its point's LDS column once, scalar weights.
// LDS: att 16K + x1 16K + xh 16K + m 32K = 80 KB -> 1 block/CU (grid 115
// < 256 CUs; occupancy irrelevant, per-block work is ~14K cyc of FMA).
// ---------------------------------------------------------------------------
__global__ __launch_bounds__(256) void kt_epilogue(
    const float* __restrict__ num, const float* __restrict__ den,
    const float* __restrict__ wo,  const float* __restrict__ x,
    const float* __restrict__ w1,  const float* __restrict__ b1,
    const float* __restrict__ g,   const float* __restrict__ bb,
    const float* __restrict__ w2,  const float* __restrict__ b2,
    float* __restrict__ out)
{
    __shared__ float att[64][64];          // [c][p]
    __shared__ float x1s[64][64];
    __shared__ float xh[64][64];
    __shared__ float ms[HIDN][64];

    const int t  = threadIdx.x;
    const int n0 = blockIdx.x * 64;
    const int og = t >> 6;
    const int p  = t & 63;
    const int n  = n0 + p;
    const int nc = (n < NSEG) ? n : (NSEG - 1);
    const bool ok = n < NSEG;

    if (t < 64) {                          // A: att = num * (1/den)
        const int tnc = (n0 + t < NSEG) ? (n0 + t) : (NSEG - 1);
        float rd[4];
#pragma unroll
        for (int h = 0; h < 4; ++h) rd[h] = 1.0f / den[h * NSEG + tnc];
#pragma unroll
        for (int c = 0; c < 64; ++c)
            att[c][t] = num[c * NSEG + tnc] * rd[c >> 4];
    }
    __syncthreads();

    {                                      // B: x1 = Wo*att + x
        float av[64];
#pragma unroll
        for (int c = 0; c < 64; ++c) av[c] = att[c][p];
#pragma unroll 4
        for (int j = 0; j < 16; ++j) {
            const int o = og * 16 + j;
            float a = 0.f;
#pragma unroll
            for (int c = 0; c < 64; ++c) a += wo[o * 64 + c] * av[c];
            x1s[o][p] = a + x[o * NSEG + nc];
        }
    }
    __syncthreads();

    if (t < 64) {                          // C: LN1
        float xv[64];
        float s = 0.f, s2 = 0.f;
#pragma unroll
        for (int c = 0; c < 64; ++c) {
            float v = x1s[c][t];
            xv[c] = v; s += v; s2 += v * v;
        }
        float mean = s * 0.015625f;
        float var  = s2 * 0.015625f - mean * mean;
        float rstd = rsqrtf(var + 1e-6f);
#pragma unroll
        for (int c = 0; c < 64; ++c)
            xh[c][t] = (xv[c] - mean) * rstd * g[c] + bb[c];
    }
    __syncthreads();

    {                                      // D: m = gelu(W1*xh + b1)
        float xv[64];
#pragma unroll
        for (int c = 0; c < 64; ++c) xv[c] = xh[c][p];
#pragma unroll 4
        for (int j = 0; j < 32; ++j) {
            const int h = og * 32 + j;
            float a = b1[h];
#pragma unroll
            for (int c = 0; c < 64; ++c) a += w1[h * 64 + c] * xv[c];
            ms[h][p] = 0.5f * a * (1.0f + erff(a * 0.70710678118654752f));
        }
    }
    __syncthreads();

    {                                      // E: out = W2*m + b2 + x1
        float acc[16];
#pragma unroll
        for (int j = 0; j < 16; ++j) acc[j] = 0.f;
        const int c0 = og * 16;
#pragma unroll
        for (int half = 0; half < 2; ++half) {
            float mr[64];
#pragma unroll
            for (int hh = 0; hh < 64; ++hh) mr[hh] = ms[half * 64 + hh][p];
#pragma unroll 8
            for (int hh = 0; hh < 64; ++hh) {
                const float mh = mr[hh];
                const int hidx = half * 64 + hh;
#pragma unroll
                for (int j = 0; j < 16; ++j)
                    acc[j] += w2[(c0 + j) * HIDN + hidx] * mh;
            }
        }
        if (ok) {
#pragma unroll
            for (int j = 0; j < 16; ++j) {
                const int c = c0 + j;
                out[c * NSEG + n] = acc[j] + b2[c] + x1s[c][p];
            }
        }
    }
}

// ---------------------------------------------------------------------------
extern "C" void kernel_launch(void* const* d_in, const int* in_sizes, int n_in,
                              void* d_out, int out_size, void* d_ws, size_t ws_size,
                              hipStream_t stream)
{
    const float* x    = (const float*)d_in[0];
    const float* wq   = (const float*)d_in[1];
    const float* wk   = (const float*)d_in[2];
    const float* wv   = (const float*)d_in[3];
    const float* wo   = (const float*)d_in[4];
    const float* w1   = (const float*)d_in[5];
    const float* b1   = (const float*)d_in[6];
    const float* w2   = (const float*)d_in[7];
    const float* b2   = (const float*)d_in[8];
    const float* ln0g = (const float*)d_in[9];
    const float* ln0b = (const float*)d_in[10];
    const float* ln1g = (const float*)d_in[11];
    const float* ln1b = (const float*)d_in[12];
    const float* qw   = (const float*)d_in[13];
    const int* out_idx = (const int*)d_in[14];
    const int* in_idx  = (const int*)d_in[15];
    float* out = (float*)d_out;

    const int NNZ = in_sizes[15];
    const int E   = NNZ / NLON;
    const size_t N64 = (size_t)NSEG * 64;

    float* ws    = (float*)d_ws;
    float* q_pl  = ws;                     // [64][NSEG]
    float* k_pl  = ws + N64;
    float* v_pl  = ws + 2 * N64;
    float* num   = ws + 3 * N64;           // [64][NSEG]  (zeroed by k1 grp1)
    float* den   = ws + 4 * N64;           // [4][NSEG]   (contiguous w/ num)
    int*   row_start = (int*)(ws + 4 * N64 + 4 * NSEG);            // [62]
    int4*  meta  = (int4*)(ws + 4 * N64 + 4 * NSEG + 64);          // [E]

    hipLaunchKernelGGL(k1_ln_qkv, dim3(115, 2), dim3(256), 0, stream,
                       x, wq, wk, wv, ln0g, ln0b, out_idx, in_idx, qw, E,
                       q_pl, k_pl, v_pl, row_start, meta, (float4*)num);
    hipLaunchKernelGGL(k2_attn, dim3(61, NCH, 4), dim3(128), 0, stream,
                       q_pl, k_pl, v_pl, meta, row_start, num, den);
    hipLaunchKernelGGL(kt_epilogue, dim3(115), dim3(256), 0, stream,
                       num, den, wo, x, w1, b1, ln1g, ln1b, w2, b2, out);
}